// Round 1
// baseline (4543.824 us; speedup 1.0000x reference)
//
#include <hip/hip_runtime.h>

#define NU 200000
#define NI 100000

// ---------------- CSR build ----------------

struct CsrBuild {
  const int* rows[6]; const int* cols[6]; const float* vals[6];
  int nE[6]; int nR[6];
  int* counts[6]; int* offs[6]; int* cursor[6];
  int* ccol[6]; float* cval[6];
};

__global__ void hist_k(CsrBuild cb) {
  int l = blockIdx.y;
  int i = blockIdx.x * blockDim.x + threadIdx.x;
  if (i < cb.nE[l]) atomicAdd(&cb.counts[l][cb.rows[l][i]], 1);
}

__global__ void scatter_k(CsrBuild cb) {
  int l = blockIdx.y;
  int i = blockIdx.x * blockDim.x + threadIdx.x;
  if (i < cb.nE[l]) {
    int r = cb.rows[l][i];
    int p = atomicAdd(&cb.cursor[l][r], 1);
    cb.ccol[l][p] = cb.cols[l][i];
    cb.cval[l][p] = cb.vals[l][i];
  }
}

// One block per list; 256 threads x 16 elems per chunk; wave-shuffle scan.
__global__ __launch_bounds__(256) void scan_k(CsrBuild cb) {
  int l = blockIdx.x;
  int n = cb.nR[l];
  const int* __restrict__ counts = cb.counts[l];
  int* __restrict__ offs = cb.offs[l];
  int* __restrict__ curp = cb.cursor[l];
  __shared__ int wsum[4];
  __shared__ int s_running;
  int t = threadIdx.x, lane = t & 63, wv = t >> 6;
  if (t == 0) s_running = 0;
  __syncthreads();
  for (int base = 0; base < n; base += 4096) {
    int v[16];
    int i0 = base + t * 16;
#pragma unroll
    for (int i = 0; i < 16; ++i) { int idx = i0 + i; v[i] = (idx < n) ? counts[idx] : 0; }
#pragma unroll
    for (int i = 1; i < 16; ++i) v[i] += v[i - 1];
    int tot = v[15], sc = tot;
#pragma unroll
    for (int o = 1; o < 64; o <<= 1) { int x = __shfl_up(sc, o, 64); if (lane >= o) sc += x; }
    if (lane == 63) wsum[wv] = sc;
    __syncthreads();
    int wbase = 0;
    for (int j = 0; j < wv; ++j) wbase += wsum[j];
    int running = s_running;
    int eb = running + wbase + (sc - tot);
#pragma unroll
    for (int i = 0; i < 16; ++i) {
      int idx = i0 + i;
      if (idx < n) { int pv = eb + (i ? v[i - 1] : 0); offs[idx] = pv; curp[idx] = pv; }
    }
    __syncthreads();
    if (t == 255) s_running = running + wbase + sc;
    __syncthreads();
  }
  if (t == 0) offs[n] = s_running;
}

// ---------------- vector helpers ----------------

template <int G> struct VT;
template <> struct VT<4> { using T = float4; };
template <> struct VT<2> { using T = float2; };
template <> struct VT<1> { using T = float; };

__device__ __forceinline__ void vset0(float4& a) { a.x = 0; a.y = 0; a.z = 0; a.w = 0; }
__device__ __forceinline__ void vset0(float2& a) { a.x = 0; a.y = 0; }
__device__ __forceinline__ void vset0(float& a) { a = 0; }
__device__ __forceinline__ void vfma(float4& a, float s, float4 b) { a.x += s * b.x; a.y += s * b.y; a.z += s * b.z; a.w += s * b.w; }
__device__ __forceinline__ void vfma(float2& a, float s, float2 b) { a.x += s * b.x; a.y += s * b.y; }
__device__ __forceinline__ void vfma(float& a, float s, float b) { a += s * b; }
__device__ __forceinline__ void vadd(float4& a, float4 b) { a.x += b.x; a.y += b.y; a.z += b.z; a.w += b.w; }
__device__ __forceinline__ void vadd(float2& a, float2 b) { a.x += b.x; a.y += b.y; }
__device__ __forceinline__ void vadd(float& a, float b) { a += b; }

// ---------------- init: embeddings -> cur buffer + acc(out) ----------------

template <int G>
__global__ __launch_bounds__(256) void init_k(const float* __restrict__ embs,
    float* __restrict__ cur, float* __restrict__ acc, int k0, int nrows) {
  const int pr = 16 * G;  // float4s per row
  long long i = (long long)blockIdx.x * blockDim.x + threadIdx.x;
  if (i >= (long long)nrows * pr) return;
  int u = (int)(i / pr);
  int rem = (int)(i % pr);
  int k = rem >> 4, d4 = rem & 15;
  float4 v = ((const float4*)(embs + ((size_t)(k0 + k) * nrows + u) * 64))[d4];
  ((float4*)(cur + (size_t)u * (64 * G) + k * 64))[d4] = v;
  ((float4*)(acc + (size_t)u * 256 + (size_t)(k0 + k) * 64))[d4] = v;
}

// ---------------- pull-mode SpMM: one wave per destination row ----------------

template <int G, typename V>
__device__ __forceinline__ void gather_rows(V& a, const float* __restrict__ x,
    int beg, int end, const int* __restrict__ col, const float* __restrict__ val, int lane) {
  for (int e0 = beg; e0 < end; e0 += 64) {
    int nn = min(64, end - e0);
    int c = 0; float vv = 0.f;
    if (lane < nn) { c = col[e0 + lane]; vv = val[e0 + lane]; }
    for (int s = 0; s < nn; ++s) {
      int cs = __shfl(c, s);
      float vs = __shfl(vv, s);
      V xv = ((const V*)(x + (size_t)cs * (64 * G)))[lane];
      vfma(a, vs, xv);
    }
  }
}

template <int G>
__global__ __launch_bounds__(256) void spmm_k(
    const float* __restrict__ xA, const float* __restrict__ xB,
    float* __restrict__ nxt, float* __restrict__ acc, int k0, int nrows, int half,
    const int* __restrict__ offA, const int* __restrict__ colA, const float* __restrict__ valA,
    const int* __restrict__ off0, const int* __restrict__ col0, const float* __restrict__ val0,
    const int* __restrict__ off1, const int* __restrict__ col1, const float* __restrict__ val1) {
  using V = typename VT<G>::T;
  int w = (int)(((long long)blockIdx.x * blockDim.x + threadIdx.x) >> 6);
  int lane = threadIdx.x & 63;
  if (w >= nrows) return;
  V a; vset0(a);
  gather_rows<G>(a, xA, offA[w], offA[w + 1], colA, valA, lane);
  const int* off = (w < half) ? off0 : off1;
  const int* col = (w < half) ? col0 : col1;
  const float* val = (w < half) ? val0 : val1;
  int lr = (w < half) ? w : w - half;
  gather_rows<G>(a, xB, off[lr], off[lr + 1], col, val, lane);
  ((V*)(nxt + (size_t)w * (64 * G)))[lane] = a;
  V* ap = (V*)(acc + (size_t)w * 256 + (size_t)k0 * 64) + lane;
  V o = *ap; vadd(o, a); *ap = o;
}

// ---------------- final transform: in-place (acc/3) @ W_k, relu ----------------

__global__ __launch_bounds__(256) void xform_k(float* __restrict__ out,
    const float* __restrict__ Wu, const float* __restrict__ Wv) {
  const int utiles = NU / 64;  // 3125
  int tile = blockIdx.x;
  float* base; const float* W; int nrows, row0;
  if (tile < utiles) { base = out; W = Wu; nrows = NU; row0 = tile * 64; }
  else { base = out + (size_t)NU * 256; W = Wv; nrows = NI; row0 = (tile - utiles) * 64; }
  __shared__ float Xs[64][68];
  __shared__ float Ws[64][68];
  int t = threadIdx.x;
  int tr = t >> 4, tc = (t & 15) * 4;
  const float inv3 = 1.f / 3.f;
  for (int k = 0; k < 4; ++k) {
#pragma unroll
    for (int i = 0; i < 4; ++i) {
      int e = t + i * 256;          // 0..1023 float4 index over 64x64 tile
      int r = e >> 4, c4 = e & 15;
      float4 wv = ((const float4*)(W + (size_t)k * 4096 + (size_t)r * 64))[c4];
      *(float4*)&Ws[r][c4 * 4] = wv;
      int row = row0 + r;
      float4 xv = make_float4(0.f, 0.f, 0.f, 0.f);
      if (row < nrows) xv = ((const float4*)(base + (size_t)row * 256 + k * 64))[c4];
      xv.x *= inv3; xv.y *= inv3; xv.z *= inv3; xv.w *= inv3;
      *(float4*)&Xs[r][c4 * 4] = xv;
    }
    __syncthreads();
    float y[4][4];
#pragma unroll
    for (int i = 0; i < 4; ++i)
#pragma unroll
      for (int j = 0; j < 4; ++j) y[i][j] = 0.f;
    for (int j = 0; j < 64; ++j) {
      float xr[4], wc[4];
#pragma unroll
      for (int i = 0; i < 4; ++i) { xr[i] = Xs[tr * 4 + i][j]; wc[i] = Ws[j][tc + i]; }
#pragma unroll
      for (int i = 0; i < 4; ++i)
#pragma unroll
        for (int jj = 0; jj < 4; ++jj) y[i][jj] += xr[i] * wc[jj];
    }
#pragma unroll
    for (int i = 0; i < 4; ++i) {
      int row = row0 + tr * 4 + i;
      if (row < nrows) {
        float4 o = make_float4(fmaxf(y[i][0], 0.f), fmaxf(y[i][1], 0.f),
                               fmaxf(y[i][2], 0.f), fmaxf(y[i][3], 0.f));
        ((float4*)(base + (size_t)row * 256 + k * 64))[t & 15] = o;
      }
    }
    __syncthreads();
  }
}

// ---------------- driver ----------------

template <int G>
static void run_passes(float* cu0, float* ci0, float* nu0, float* ni0,
                       float* outU, float* outI,
                       const float* uemb, const float* iemb,
                       const CsrBuild& cb, hipStream_t stream) {
  for (int k0 = 0; k0 < 4; k0 += G) {
    float* cu = cu0; float* ci = ci0; float* nu_ = nu0; float* ni_ = ni0;
    long long tu = (long long)NU * 16 * G, ti = (long long)NI * 16 * G;
    init_k<G><<<(unsigned)((tu + 255) / 256), 256, 0, stream>>>(uemb, cu, outU, k0, NU);
    init_k<G><<<(unsigned)((ti + 255) / 256), 256, 0, stream>>>(iemb, ci, outI, k0, NI);
    for (int layer = 0; layer < 2; ++layer) {
      spmm_k<G><<<(NU + 3) / 4, 256, 0, stream>>>(cu, ci, nu_, outU, k0, NU, NU / 2,
          cb.offs[0], cb.ccol[0], cb.cval[0],
          cb.offs[1], cb.ccol[1], cb.cval[1],
          cb.offs[2], cb.ccol[2], cb.cval[2]);
      spmm_k<G><<<(NI + 3) / 4, 256, 0, stream>>>(ci, cu, ni_, outI, k0, NI, NI / 2,
          cb.offs[5], cb.ccol[5], cb.cval[5],
          cb.offs[3], cb.ccol[3], cb.cval[3],
          cb.offs[4], cb.ccol[4], cb.cval[4]);
      float* tmp;
      tmp = cu; cu = nu_; nu_ = tmp;
      tmp = ci; ci = ni_; ni_ = tmp;
    }
  }
}

extern "C" void kernel_launch(void* const* d_in, const int* in_sizes, int n_in,
                              void* d_out, int out_size, void* d_ws, size_t ws_size,
                              hipStream_t stream) {
  CsrBuild cb;
  const int rows_idx[6] = {0, 3, 6, 9, 12, 15};
  const int nRl[6] = {NU, NU / 2, NU / 2, NI / 2, NI / 2, NI};
  size_t totE = 0, totR = 0;
  for (int l = 0; l < 6; ++l) {
    cb.rows[l] = (const int*)d_in[rows_idx[l]];
    cb.cols[l] = (const int*)d_in[rows_idx[l] + 1];
    cb.vals[l] = (const float*)d_in[rows_idx[l] + 2];
    cb.nE[l] = in_sizes[rows_idx[l]];
    cb.nR[l] = nRl[l];
    totE += (size_t)cb.nE[l];
    totR += (size_t)nRl[l];
  }

  size_t csr_bytes = ((totR * 4 + 255) & ~(size_t)255) * 2
                   + (((totR + 6) * 4 + 255) & ~(size_t)255)
                   + ((totE * 4 + 255) & ~(size_t)255) * 2 + 4096;
  auto need = [&](int g) {
    return (size_t)(NU + NI) * 64ULL * (size_t)g * 4ULL * 2ULL + csr_bytes + 4096;
  };
  int G = (ws_size >= need(4)) ? 4 : (ws_size >= need(2)) ? 2 : 1;

  char* basep = (char*)d_ws; size_t off = 0;
  auto alloc = [&](size_t b) -> void* {
    void* r = basep + off; off = (off + b + 255) & ~(size_t)255; return r;
  };
  float* cur_u = (float*)alloc((size_t)NU * 64 * G * 4);
  float* cur_i = (float*)alloc((size_t)NI * 64 * G * 4);
  float* nxt_u = (float*)alloc((size_t)NU * 64 * G * 4);
  float* nxt_i = (float*)alloc((size_t)NI * 64 * G * 4);
  int* counts_all = (int*)alloc(totR * 4);
  int* offs_all = (int*)alloc((totR + 6) * 4);
  int* cursor_all = (int*)alloc(totR * 4);
  int* ccol_all = (int*)alloc(totE * 4);
  float* cval_all = (float*)alloc(totE * 4);

  size_t ro = 0, oo = 0, eo = 0;
  for (int l = 0; l < 6; ++l) {
    cb.counts[l] = counts_all + ro;
    cb.cursor[l] = cursor_all + ro;
    cb.offs[l] = offs_all + oo;
    cb.ccol[l] = ccol_all + eo;
    cb.cval[l] = cval_all + eo;
    ro += (size_t)nRl[l]; oo += (size_t)nRl[l] + 1; eo += (size_t)cb.nE[l];
  }

  hipMemsetAsync(counts_all, 0, totR * 4, stream);
  int maxE = 0;
  for (int l = 0; l < 6; ++l) if (cb.nE[l] > maxE) maxE = cb.nE[l];
  dim3 eg((maxE + 255) / 256, 6);
  hist_k<<<eg, 256, 0, stream>>>(cb);
  scan_k<<<6, 256, 0, stream>>>(cb);
  scatter_k<<<eg, 256, 0, stream>>>(cb);

  float* outU = (float*)d_out;
  float* outI = outU + (size_t)NU * 256;
  const float* user_embs = (const float*)d_in[18];
  const float* item_embs = (const float*)d_in[19];
  const float* W_u = (const float*)d_in[20];
  const float* W_v = (const float*)d_in[21];

  switch (G) {
    case 4: run_passes<4>(cur_u, cur_i, nxt_u, nxt_i, outU, outI, user_embs, item_embs, cb, stream); break;
    case 2: run_passes<2>(cur_u, cur_i, nxt_u, nxt_i, outU, outI, user_embs, item_embs, cb, stream); break;
    default: run_passes<1>(cur_u, cur_i, nxt_u, nxt_i, outU, outI, user_embs, item_embs, cb, stream); break;
  }

  int tiles = NU / 64 + (NI + 63) / 64;
  xform_k<<<tiles, 256, 0, stream>>>((float*)d_out, W_u, W_v);
}

// Round 2
// 2888.921 us; speedup vs baseline: 1.5728x; 1.5728x over previous
//
#include <hip/hip_runtime.h>

#define NU 200000
#define NI 100000

// Global row-space layout (concatenated CSR over all 6 lists):
//  l0 u2u    rows NU      base 0
//  l1 u2i f0 rows NU/2    base 200000
//  l2 u2i f1 rows NU/2    base 300000
//  l3 i2u f0 rows NI/2    base 400000
//  l4 i2u f1 rows NI/2    base 450000
//  l5 i2i    rows NI      base 500000
// totR = 600000. Edges of list l are contiguous in edges_all at
// [offs[base_l + r] ...), because the global exclusive scan over the
// concatenated counts puts each list's segment exactly after the previous.

#define TOTR 600000

struct Bld {
  const int* rows[6]; const int* cols[6]; const float* vals[6];
  int nE[6]; int base[6];
  int* counts; int* cursor;
  uint2* edges;
};

// ---------------- bf16 helpers ----------------

__device__ __forceinline__ unsigned bfr(float f) {  // fp32 -> bf16 bits, RTNE
  unsigned u = __float_as_uint(f);
  return (u + 0x7FFFu + ((u >> 16) & 1u)) >> 16;
}
__device__ __forceinline__ float blo(unsigned p) { return __uint_as_float(p << 16); }
__device__ __forceinline__ float bhi(unsigned p) { return __uint_as_float(p & 0xFFFF0000u); }

// ---------------- CSR build ----------------

__global__ void hist_k(Bld b) {
  int l = blockIdx.y;
  int i = blockIdx.x * blockDim.x + threadIdx.x;
  if (i < b.nE[l]) atomicAdd(&b.counts[b.base[l] + b.rows[l][i]], 1);
}

__global__ void scatter_k(Bld b) {
  int l = blockIdx.y;
  int i = blockIdx.x * blockDim.x + threadIdx.x;
  if (i < b.nE[l]) {
    int r = b.base[l] + b.rows[l][i];
    int p = atomicAdd(&b.cursor[r], 1);
    b.edges[p] = make_uint2((unsigned)b.cols[l][i], __float_as_uint(b.vals[l][i]));
  }
}

// scanA: per-4096-chunk totals
__global__ __launch_bounds__(256) void scanA_k(const int* __restrict__ counts,
                                               int* __restrict__ bsum, int n) {
  int t = threadIdx.x;
  int i0 = blockIdx.x * 4096 + t * 16;
  int s = 0;
#pragma unroll
  for (int i = 0; i < 16; ++i) { int idx = i0 + i; if (idx < n) s += counts[idx]; }
#pragma unroll
  for (int o = 1; o < 64; o <<= 1) s += __shfl_xor(s, o, 64);
  __shared__ int ws[4];
  if ((t & 63) == 0) ws[t >> 6] = s;
  __syncthreads();
  if (t == 0) bsum[blockIdx.x] = ws[0] + ws[1] + ws[2] + ws[3];
}

// scanB: exclusive scan of chunk totals (single block), writes grand total
__global__ __launch_bounds__(256) void scanB_k(int* __restrict__ bsum,
                                               int* __restrict__ offs, int nb, int n) {
  __shared__ int s_run;
  __shared__ int wsum[4];
  int t = threadIdx.x, lane = t & 63, wv = t >> 6;
  if (t == 0) s_run = 0;
  __syncthreads();
  for (int base = 0; base < nb; base += 256) {
    int v = (base + t < nb) ? bsum[base + t] : 0;
    int sc = v;
#pragma unroll
    for (int o = 1; o < 64; o <<= 1) { int x = __shfl_up(sc, o, 64); if (lane >= o) sc += x; }
    if (lane == 63) wsum[wv] = sc;
    __syncthreads();
    int wb = 0;
    for (int j = 0; j < wv; ++j) wb += wsum[j];
    int run = s_run;
    if (base + t < nb) bsum[base + t] = run + wb + sc - v;
    __syncthreads();
    if (t == 255) s_run = run + wsum[0] + wsum[1] + wsum[2] + wsum[3];
    __syncthreads();
  }
  if (t == 0) { bsum[nb] = s_run; offs[n] = s_run; }
}

// scanC: full exclusive scan, offs + cursor
__global__ __launch_bounds__(256) void scanC_k(const int* __restrict__ counts,
    const int* __restrict__ bsum, int* __restrict__ offs, int* __restrict__ cursor, int n) {
  int t = threadIdx.x, lane = t & 63, wv = t >> 6;
  int i0 = blockIdx.x * 4096 + t * 16;
  int v[16];
  int s = 0;
#pragma unroll
  for (int i = 0; i < 16; ++i) {
    int idx = i0 + i;
    int c = (idx < n) ? counts[idx] : 0;
    s += c; v[i] = s;
  }
  int tot = s, sc = tot;
#pragma unroll
  for (int o = 1; o < 64; o <<= 1) { int x = __shfl_up(sc, o, 64); if (lane >= o) sc += x; }
  __shared__ int wsum[4];
  if (lane == 63) wsum[wv] = sc;
  __syncthreads();
  int wb = 0;
  for (int j = 0; j < wv; ++j) wb += wsum[j];
  int ebase = bsum[blockIdx.x] + wb + (sc - tot);
#pragma unroll
  for (int i = 0; i < 16; ++i) {
    int idx = i0 + i;
    if (idx < n) {
      int pv = ebase + (i ? v[i - 1] : 0);
      offs[idx] = pv; cursor[idx] = pv;
    }
  }
}

// ---------------- init: fp32 embs [4][N][64] -> bf16 buf [N][256] ----------------

__global__ __launch_bounds__(256) void init_k(const float* __restrict__ embs,
                                              uint2* __restrict__ buf, int nrows) {
  int idx = blockIdx.x * 256 + threadIdx.x;  // one uint2 (4 elems) per thread
  if (idx >= nrows * 64) return;
  int u = idx >> 6, q = idx & 63;
  int k = q >> 4, d = (q & 15) * 4;
  const float4 f = *(const float4*)(embs + ((size_t)k * nrows + u) * 64 + d);
  uint2 o;
  o.x = (bfr(f.y) << 16) | bfr(f.x);
  o.y = (bfr(f.w) << 16) | bfr(f.z);
  buf[idx] = o;
}

// ---------------- pull-mode SpMM over bf16 rows ----------------

__device__ __forceinline__ void gacc(float a[4], const uint2* __restrict__ x,
    int beg, int end, const uint2* __restrict__ edges, int lane) {
  for (int e0 = beg; e0 < end; e0 += 64) {
    int nn = min(64, end - e0);
    uint2 ev = make_uint2(0u, 0u);
    if (lane < nn) ev = edges[e0 + lane];
    int full = nn & ~7;
    int s = 0;
    for (; s < full; s += 8) {
      unsigned cs[8]; float vs[8]; uint2 d[8];
#pragma unroll
      for (int j = 0; j < 8; ++j) {
        cs[j] = (unsigned)__shfl((int)ev.x, s + j);
        vs[j] = __uint_as_float((unsigned)__shfl((int)ev.y, s + j));
      }
#pragma unroll
      for (int j = 0; j < 8; ++j) d[j] = x[cs[j] * 64u + (unsigned)lane];
#pragma unroll
      for (int j = 0; j < 8; ++j) {
        a[0] += vs[j] * blo(d[j].x);
        a[1] += vs[j] * bhi(d[j].x);
        a[2] += vs[j] * blo(d[j].y);
        a[3] += vs[j] * bhi(d[j].y);
      }
    }
    for (; s < nn; ++s) {
      unsigned c = (unsigned)__shfl((int)ev.x, s);
      float v = __uint_as_float((unsigned)__shfl((int)ev.y, s));
      uint2 dd = x[c * 64u + (unsigned)lane];
      a[0] += v * blo(dd.x);
      a[1] += v * bhi(dd.x);
      a[2] += v * blo(dd.y);
      a[3] += v * bhi(dd.y);
    }
  }
}

__global__ __launch_bounds__(256) void spmm_k(
    const uint2* __restrict__ xA, const uint2* __restrict__ xB,
    uint2* __restrict__ nxt, int nrows, int half,
    const int* __restrict__ offA,
    const int* __restrict__ off0, const int* __restrict__ off1,
    const uint2* __restrict__ edges) {
  int w = (blockIdx.x * 256 + threadIdx.x) >> 6;
  int lane = threadIdx.x & 63;
  if (w >= nrows) return;
  float a[4] = {0.f, 0.f, 0.f, 0.f};
  gacc(a, xA, offA[w], offA[w + 1], edges, lane);
  const int* off = (w < half) ? off0 : off1;
  int lr = (w < half) ? w : w - half;
  gacc(a, xB, off[lr], off[lr + 1], edges, lane);
  uint2 o;
  o.x = (bfr(a[1]) << 16) | bfr(a[0]);
  o.y = (bfr(a[3]) << 16) | bfr(a[2]);
  nxt[(size_t)w * 64 + lane] = o;
}

// ---------------- final: out = relu(((e0 + l1 + l2)/3) @ W_k) ----------------

__global__ __launch_bounds__(256) void xform_k(float* __restrict__ out,
    const float* __restrict__ uembs, const float* __restrict__ iembs,
    const uint2* __restrict__ u1, const uint2* __restrict__ u0,
    const uint2* __restrict__ i1, const uint2* __restrict__ i0,
    const float* __restrict__ Wu, const float* __restrict__ Wv) {
  const int utiles = NU / 64;  // 3125
  int tile = blockIdx.x;
  const float* embs; const uint2 *b1, *b0; const float* W; float* base; int nrows, row0;
  if (tile < utiles) {
    embs = uembs; b1 = u1; b0 = u0; W = Wu; base = out; nrows = NU; row0 = tile * 64;
  } else {
    embs = iembs; b1 = i1; b0 = i0; W = Wv; base = out + (size_t)NU * 256; nrows = NI;
    row0 = (tile - utiles) * 64;
  }
  __shared__ float Xs[64][68];
  __shared__ float Ws[64][68];
  int t = threadIdx.x;
  int tr = t >> 4, tc = (t & 15) * 4;
  const float inv3 = 1.f / 3.f;
  for (int k = 0; k < 4; ++k) {
#pragma unroll
    for (int i = 0; i < 4; ++i) {
      int e = t + i * 256;  // 0..1023 float4-slots over the 64x64 tile
      int r = e >> 4, c4 = e & 15;
      float4 wv = ((const float4*)(W + (size_t)k * 4096 + (size_t)r * 64))[c4];
      *(float4*)&Ws[r][c4 * 4] = wv;
      int row = row0 + r;
      float4 xv = make_float4(0.f, 0.f, 0.f, 0.f);
      if (row < nrows) {
        const float4 e0 = *(const float4*)(embs + ((size_t)k * nrows + row) * 64 + c4 * 4);
        uint2 p1 = b1[(size_t)row * 64 + k * 16 + c4];
        uint2 p2 = b0[(size_t)row * 64 + k * 16 + c4];
        xv.x = (e0.x + blo(p1.x) + blo(p2.x)) * inv3;
        xv.y = (e0.y + bhi(p1.x) + bhi(p2.x)) * inv3;
        xv.z = (e0.z + blo(p1.y) + blo(p2.y)) * inv3;
        xv.w = (e0.w + bhi(p1.y) + bhi(p2.y)) * inv3;
      }
      *(float4*)&Xs[r][c4 * 4] = xv;
    }
    __syncthreads();
    float y[4][4];
#pragma unroll
    for (int i = 0; i < 4; ++i)
#pragma unroll
      for (int j = 0; j < 4; ++j) y[i][j] = 0.f;
    for (int j = 0; j < 64; ++j) {
      float xr[4], wc[4];
#pragma unroll
      for (int i = 0; i < 4; ++i) { xr[i] = Xs[tr * 4 + i][j]; wc[i] = Ws[j][tc + i]; }
#pragma unroll
      for (int i = 0; i < 4; ++i)
#pragma unroll
        for (int jj = 0; jj < 4; ++jj) y[i][jj] += xr[i] * wc[jj];
    }
#pragma unroll
    for (int i = 0; i < 4; ++i) {
      int row = row0 + tr * 4 + i;
      if (row < nrows) {
        float4 o = make_float4(fmaxf(y[i][0], 0.f), fmaxf(y[i][1], 0.f),
                               fmaxf(y[i][2], 0.f), fmaxf(y[i][3], 0.f));
        ((float4*)(base + (size_t)row * 256 + k * 64))[t & 15] = o;
      }
    }
    __syncthreads();
  }
}

// ---------------- driver ----------------

extern "C" void kernel_launch(void* const* d_in, const int* in_sizes, int n_in,
                              void* d_out, int out_size, void* d_ws, size_t ws_size,
                              hipStream_t stream) {
  Bld b;
  const int rows_idx[6] = {0, 3, 6, 9, 12, 15};
  const int nRl[6] = {NU, NU / 2, NU / 2, NI / 2, NI / 2, NI};
  int bases[6]; int acc_base = 0;
  size_t totE = 0;
  for (int l = 0; l < 6; ++l) {
    b.rows[l] = (const int*)d_in[rows_idx[l]];
    b.cols[l] = (const int*)d_in[rows_idx[l] + 1];
    b.vals[l] = (const float*)d_in[rows_idx[l] + 2];
    b.nE[l] = in_sizes[rows_idx[l]];
    bases[l] = acc_base; b.base[l] = acc_base;
    acc_base += nRl[l];
    totE += (size_t)b.nE[l];
  }
  const int totR = acc_base;  // 600000
  const int nb = (totR + 4095) / 4096;

  char* basep = (char*)d_ws; size_t off = 0;
  auto alloc = [&](size_t bytes) -> void* {
    void* r = basep + off; off = (off + bytes + 255) & ~(size_t)255; return r;
  };
  uint2* bufU0 = (uint2*)alloc((size_t)NU * 64 * 8);
  uint2* bufU1 = (uint2*)alloc((size_t)NU * 64 * 8);
  uint2* bufI0 = (uint2*)alloc((size_t)NI * 64 * 8);
  uint2* bufI1 = (uint2*)alloc((size_t)NI * 64 * 8);
  int* counts = (int*)alloc((size_t)totR * 4);
  int* offs = (int*)alloc((size_t)(totR + 1) * 4);
  int* cursor = (int*)alloc((size_t)totR * 4);
  int* bsum = (int*)alloc((size_t)(nb + 1) * 4);
  uint2* edges = (uint2*)alloc(totE * 8);
  b.counts = counts; b.cursor = cursor; b.edges = edges;

  hipMemsetAsync(counts, 0, (size_t)totR * 4, stream);
  int maxE = 0;
  for (int l = 0; l < 6; ++l) if (b.nE[l] > maxE) maxE = b.nE[l];
  dim3 eg((maxE + 255) / 256, 6);
  hist_k<<<eg, 256, 0, stream>>>(b);
  scanA_k<<<nb, 256, 0, stream>>>(counts, bsum, totR);
  scanB_k<<<1, 256, 0, stream>>>(bsum, offs, nb, totR);
  scanC_k<<<nb, 256, 0, stream>>>(counts, bsum, offs, cursor, totR);
  scatter_k<<<eg, 256, 0, stream>>>(b);

  const float* user_embs = (const float*)d_in[18];
  const float* item_embs = (const float*)d_in[19];
  const float* W_u = (const float*)d_in[20];
  const float* W_v = (const float*)d_in[21];

  init_k<<<(NU * 64 + 255) / 256, 256, 0, stream>>>(user_embs, bufU0, NU);
  init_k<<<(NI * 64 + 255) / 256, 256, 0, stream>>>(item_embs, bufI0, NI);

  // layer 1: read U0/I0 -> write U1/I1
  spmm_k<<<(NU + 3) / 4, 256, 0, stream>>>(bufU0, bufI0, bufU1, NU, NU / 2,
      offs + bases[0], offs + bases[1], offs + bases[2], edges);
  spmm_k<<<(NI + 3) / 4, 256, 0, stream>>>(bufI0, bufU0, bufI1, NI, NI / 2,
      offs + bases[5], offs + bases[3], offs + bases[4], edges);
  // layer 2: read U1/I1 -> write U0/I0 (e0 is re-readable from d_in)
  spmm_k<<<(NU + 3) / 4, 256, 0, stream>>>(bufU1, bufI1, bufU0, NU, NU / 2,
      offs + bases[0], offs + bases[1], offs + bases[2], edges);
  spmm_k<<<(NI + 3) / 4, 256, 0, stream>>>(bufI1, bufU1, bufI0, NI, NI / 2,
      offs + bases[5], offs + bases[3], offs + bases[4], edges);

  int tiles = NU / 64 + (NI + 63) / 64;
  xform_k<<<tiles, 256, 0, stream>>>((float*)d_out, user_embs, item_embs,
      bufU1, bufU0, bufI1, bufI0, W_u, W_v);
}